// Round 5
// baseline (6558.463 us; speedup 1.0000x reference)
//
#include <hip/hip_runtime.h>
#include <math.h>

#define VOCAB 8000
#define EMB   512
#define HID   1024
#define SEQ_L 1024
#define G3    (3*HID)
#define NWG   64          // recurrence blocks
#define NWORK 192         // worker blocks
#define NITEM 224         // 48 gi_enc + 48 gi_dec + 128 score quads
#define POISON 0xAAAAAAAAu
#define RLX __ATOMIC_RELAXED
#define AGT __HIP_MEMORY_SCOPE_AGENT

typedef float v2f __attribute__((ext_vector_type(2)));
typedef float v4f __attribute__((ext_vector_type(4)));

// 16B load that bypasses L1+L2 (reads the Infinity Cache coherence point)
__device__ __forceinline__ v4f ic_load4(const float* p) {
  v4f r;
  asm volatile("global_load_dwordx4 %0, %1, off sc0 sc1\n\ts_waitcnt vmcnt(0)"
               : "=v"(r) : "v"(p) : "memory");
  return r;
}
__device__ __forceinline__ bool any_poison4(v4f v) {
  return __float_as_uint(v.x) == POISON || __float_as_uint(v.y) == POISON ||
         __float_as_uint(v.z) == POISON || __float_as_uint(v.w) == POISON;
}
// publish with anti-poison squash (atomicExch executes at Infinity Cache)
__device__ __forceinline__ void publishf(float* p, float v) {
  if (__float_as_uint(v) == POISON) v = __uint_as_float(POISON ^ 1u);
  atomicExch(p, v);
}
// sum within each 16-lane row, VALU-only via DPP
__device__ __forceinline__ float row16_sum(float x) {
  int v = __float_as_int(x);
  x += __int_as_float(__builtin_amdgcn_update_dpp(0, v, 0xB1,  0xF, 0xF, false)); v = __float_as_int(x);
  x += __int_as_float(__builtin_amdgcn_update_dpp(0, v, 0x4E,  0xF, 0xF, false)); v = __float_as_int(x);
  x += __int_as_float(__builtin_amdgcn_update_dpp(0, v, 0x141, 0xF, 0xF, false)); v = __float_as_int(x);
  x += __int_as_float(__builtin_amdgcn_update_dpp(0, v, 0x140, 0xF, 0xF, false));
  return x;
}

// ---------------- prep: dec_in + valid mask ----------------
__global__ __launch_bounds__(1024) void prep_kernel(
    const int* __restrict__ target, const int* __restrict__ sos_p,
    const int* __restrict__ eos_p, int* __restrict__ dec_in,
    float* __restrict__ valid)
{
  int t = threadIdx.x;
  int eos = eos_p[0];
  dec_in[t] = (t == 0) ? sos_p[0] : target[t - 1];
  bool ne = (target[t] != eos);
  unsigned long long b = __ballot(ne);
  int lane = t & 63, w = t >> 6;
  __shared__ unsigned long long wb[16];
  if (lane == 0) wb[w] = b;
  __syncthreads();
  bool ok = (((~b) & ((1ull << lane) - 1ull)) == 0ull);
  for (int i = 0; i < 16; i++)
    if (i < w) ok = ok && (wb[i] == ~0ull);
  valid[t] = ok ? 1.0f : 0.0f;
}

// ---------------- 256-thread 128x128 fp32 NT GEMM sub-tile -----------------
// AMODE 0: plain A (optional gather idx). AMODE 1: sentinel-wait on A's last
// row (poison poll at IC), then x4 sc0/sc1 staging loads.
// CMODE 0: C published via atomicExch (IC-visible mid-kernel).
// CMODE 1: plain C store x rowscale[m].
// pace: optional single-dword poison poll before starting (throttles producers).
template<int AMODE, int CMODE>
__device__ void gemm_tile(const float* __restrict__ A, const int* __restrict__ idx,
                          const float* __restrict__ B, const float* __restrict__ bias,
                          const float* __restrict__ rowscale, float* __restrict__ C,
                          int N, int K, int bm, int bn, bool active,
                          const float* pace, float (*As)[132], float (*Bs)[132], int stid)
{
  if (!active) {
    for (int t = 0, e = 2 * (K / 16); t < e; t++) __syncthreads();
    return;
  }
  if (pace) {
    float v = __hip_atomic_load((float*)pace, RLX, AGT);
    while (__float_as_uint(v) == POISON) {
      __builtin_amdgcn_s_sleep(8);
      v = __hip_atomic_load((float*)pace, RLX, AGT);
    }
  }
  if (AMODE == 1) {   // sentinel: full poll of A row bm+127 => rows <= bm+127 visible
    const float* sp = A + (size_t)(bm + 127) * K + 4 * stid;
    v4f sv = ic_load4(sp);
    while (any_poison4(sv)) { __builtin_amdgcn_s_sleep(2); sv = ic_load4(sp); }
  }
  const int tx = stid & 15, ty = stid >> 4;
  float acc[8][8];
#pragma unroll
  for (int i = 0; i < 8; i++)
#pragma unroll
    for (int jj = 0; jj < 8; jj++) acc[i][jj] = 0.f;

  for (int k0 = 0; k0 < K; k0 += 16) {
    __syncthreads();
#pragma unroll
    for (int r = 0; r < 2; r++) {
      int v = stid + 256 * r;
      int row = v >> 2;
      int kq = (v & 3) << 2;
      int m = bm + row;
      v4f av;
      if (AMODE == 0) {
        const float* ab = A + (size_t)(idx ? idx[m] : m) * K + k0 + kq;
        av = *(const v4f*)ab;
      } else {
        av = ic_load4(A + (size_t)m * K + k0 + kq);
      }
      As[kq + 0][row] = av.x; As[kq + 1][row] = av.y;
      As[kq + 2][row] = av.z; As[kq + 3][row] = av.w;
      int n = bn + row;
      v4f bv = (v4f){0.f, 0.f, 0.f, 0.f};
      if (n < N) bv = *(const v4f*)(B + (size_t)n * K + k0 + kq);
      Bs[kq + 0][row] = bv.x; Bs[kq + 1][row] = bv.y;
      Bs[kq + 2][row] = bv.z; Bs[kq + 3][row] = bv.w;
    }
    __syncthreads();
#pragma unroll
    for (int k = 0; k < 16; k++) {
      float am[8], bb[8];
      *(v4f*)&am[0] = *(const v4f*)&As[k][ty * 8];
      *(v4f*)&am[4] = *(const v4f*)&As[k][ty * 8 + 4];
      *(v4f*)&bb[0] = *(const v4f*)&Bs[k][tx * 8];
      *(v4f*)&bb[4] = *(const v4f*)&Bs[k][tx * 8 + 4];
#pragma unroll
      for (int i = 0; i < 8; i++)
#pragma unroll
        for (int jj = 0; jj < 8; jj++)
          acc[i][jj] += am[i] * bb[jj];
    }
  }
#pragma unroll
  for (int i = 0; i < 8; i++) {
    int m = bm + ty * 8 + i;
#pragma unroll
    for (int jj = 0; jj < 8; jj++) {
      int n = bn + tx * 8 + jj;
      if (n < N) {
        float vv = acc[i][jj] + bias[n];
        if (CMODE == 0) publishf(&C[(size_t)m * N + n], vv);
        else            C[(size_t)m * N + n] = vv * rowscale[m];
      }
    }
  }
}

// ---------------- fused persistent kernel -----------------------------------
__global__ __launch_bounds__(1024, 1) void fused_kernel(
    const float* __restrict__ enc_whh, const float* __restrict__ enc_bhh,
    const float* __restrict__ dec_whh, const float* __restrict__ dec_bhh,
    const float* __restrict__ enc_state, const int* __restrict__ char_seq,
    const int* __restrict__ dec_in, const float* __restrict__ valid,
    const float* __restrict__ emb,
    const float* __restrict__ enc_wih, const float* __restrict__ enc_bih,
    const float* __restrict__ dec_wih, const float* __restrict__ dec_bih,
    const float* __restrict__ out_w, const float* __restrict__ out_b,
    float* gi_enc, float* gi_dec, float* hbuf, float* out_scores)
{
  __shared__ __align__(16) float As[4][16][132];
  __shared__ __align__(16) float Bs[4][16][132];
  __shared__ __align__(16) float hLDS[HID];

  const int tid = threadIdx.x;

  if (blockIdx.x < NWG) {
    // ================= recurrence =================
    const int wg   = blockIdx.x;
    const int lane = tid & 63;
    const int w    = tid >> 6;           // wave id = owned h element within slice
    const int j    = wg * 16 + w;        // owned global h index (per wave)

    // self-compute gi_enc rows 0..63, out-slice [wg*48, wg*48+48)  (~3 us)
#pragma unroll
    for (int p = 0; p < 3; p++) {
      int flat = p * 1024 + tid;         // 0..3071
      int r = flat / 48;
      int e = wg * 48 + (flat - r * 48);
      const float* x  = emb + (size_t)char_seq[r] * EMB;
      const float* wr = enc_wih + (size_t)e * EMB;
      float a = enc_bih[e];
      for (int k = 0; k < EMB; k += 4) {
        v4f xv = *(const v4f*)(x + k);
        v4f wv4 = *(const v4f*)(wr + k);
        a += xv.x * wv4.x + xv.y * wv4.y + xv.z * wv4.z + xv.w * wv4.w;
      }
      publishf(&gi_enc[(size_t)r * G3 + e], a);
    }

    // publish h0 slice; warm rows 1..16 into IC
    if (lane == 0) publishf(&hbuf[j], enc_state[j]);
    if (tid >= 960 && tid < 976)
      atomicOr((unsigned int*)&hbuf[(size_t)(tid - 959) * HID + wg * 16], 0u);

    // weights: wave w owns whh rows {w, 16+w, 32+w} of the block slice
    v2f wv[3][8];
#pragma unroll
    for (int g = 0; g < 3; g++) {
      const float* wrow = enc_whh + (size_t)(g * HID + j) * HID + lane * 16;
#pragma unroll
      for (int u = 0; u < 4; u++) {
        v4f t4 = *(const v4f*)(wrow + u * 4);
        wv[g][2 * u]     = (v2f){t4.x, t4.y};
        wv[g][2 * u + 1] = (v2f){t4.z, t4.w};
      }
    }
    float bhr = enc_bhh[j], bhz = enc_bhh[HID + j], bhn = enc_bhh[2 * HID + j];

    for (int s = 1; s <= 2 * SEQ_L; s++) {
      if (s == SEQ_L + 1) {              // decoder weights
#pragma unroll
        for (int g = 0; g < 3; g++) {
          const float* wrow = dec_whh + (size_t)(g * HID + j) * HID + lane * 16;
#pragma unroll
          for (int u = 0; u < 4; u++) {
            v4f t4 = *(const v4f*)(wrow + u * 4);
            wv[g][2 * u]     = (v2f){t4.x, t4.y};
            wv[g][2 * u + 1] = (v2f){t4.z, t4.w};
          }
        }
        bhr = dec_bhh[j]; bhz = dec_bhh[HID + j]; bhn = dec_bhh[2 * HID + j];
      }
      if (tid == 976 && s + 16 <= 2 * SEQ_L)
        atomicOr((unsigned int*)&hbuf[(size_t)(s + 16) * HID + wg * 16], 0u);

      // gi prefetch (lane0 of each wave), issued before the h poll
      float gir = 0.f, giz = 0.f, gin = 0.f;
      int cs = 1;
      const float* gi = (s <= SEQ_L) ? (gi_enc + (size_t)(s - 1) * G3)
                                     : (gi_dec + (size_t)(s - SEQ_L - 1) * G3);
      if (lane == 0) {
        gir = __hip_atomic_load((float*)&gi[j],           RLX, AGT);
        giz = __hip_atomic_load((float*)&gi[HID + j],     RLX, AGT);
        gin = __hip_atomic_load((float*)&gi[2 * HID + j], RLX, AGT);
        if (s <= SEQ_L) cs = char_seq[s - 1];
      }
      // poll h_{s-1}: 256 threads x 16B, store XOR-swizzled into LDS
      if (tid < 256) {
        const float* hp = hbuf + (size_t)(s - 1) * HID + 4 * tid;
        v4f hv = ic_load4(hp);
        while (any_poison4(hv)) hv = ic_load4(hp);
        int us = tid ^ ((tid >> 3) & 7);
        *(v4f*)&hLDS[us * 4] = hv;
      }
      if (lane == 0) {                    // gi stragglers (startup only)
        while (__float_as_uint(gir) == POISON)
          gir = __hip_atomic_load((float*)&gi[j], RLX, AGT);
        while (__float_as_uint(giz) == POISON)
          giz = __hip_atomic_load((float*)&gi[HID + j], RLX, AGT);
        while (__float_as_uint(gin) == POISON)
          gin = __hip_atomic_load((float*)&gi[2 * HID + j], RLX, AGT);
      }
      __syncthreads();                    // the ONLY barrier per step
      int uj = j >> 2, usj = uj ^ ((uj >> 3) & 7);
      float hold = hLDS[usj * 4 + (j & 3)];
      // 48 MACs/thread on b128 LDS fragments
      v2f acc2[3] = {(v2f){0.f, 0.f}, (v2f){0.f, 0.f}, (v2f){0.f, 0.f}};
#pragma unroll
      for (int u = 0; u < 4; u++) {
        int uu = lane * 4 + u, s2 = uu ^ ((uu >> 3) & 7);
        v4f hv = *(const v4f*)&hLDS[s2 * 4];
        v2f h0 = (v2f){hv.x, hv.y}, h1 = (v2f){hv.z, hv.w};
#pragma unroll
        for (int g = 0; g < 3; g++) {
          acc2[g] = __builtin_elementwise_fma(wv[g][2 * u], h0, acc2[g]);
          acc2[g] = __builtin_elementwise_fma(wv[g][2 * u + 1], h1, acc2[g]);
        }
      }
      // full 64-lane reduce: DPP within 16, shfl_xor across groups
      float gh[3];
#pragma unroll
      for (int g = 0; g < 3; g++) {
        float t = row16_sum(acc2[g].x + acc2[g].y);
        t += __shfl_xor(t, 16, 64);
        t += __shfl_xor(t, 32, 64);
        gh[g] = t;
      }
      if (lane == 0) {
        float ghr = gh[0] + bhr, ghz = gh[1] + bhz, ghn = gh[2] + bhn;
        float r = __builtin_amdgcn_rcpf(1.f + __expf(-(gir + ghr)));
        float z = __builtin_amdgcn_rcpf(1.f + __expf(-(giz + ghz)));
        float x = gin + r * ghn;
        float e = __expf(2.f * x);
        float n = 1.f - 2.f * __builtin_amdgcn_rcpf(e + 1.f);   // fast tanh
        float hnew = (1.f - z) * n + z * hold;
        if (s <= SEQ_L && cs == 0) hnew = hold;                 // encoder mask
        publishf(&hbuf[(size_t)s * HID + j], hnew);
      }
      // no second barrier: pollers can't overwrite hLDS until row s is fully
      // published, which requires every local wave to have finished its reads.
    }
  } else {
    // ================= GEMM workers =================
    const int wid  = blockIdx.x - NWG;
    const int sub  = tid >> 8;
    const int stid = tid & 255;
    float* hdec = hbuf + (size_t)(SEQ_L + 1) * HID;

    for (int item = wid; item < NITEM; item += NWORK) {
      if (item < 48) {            // gi_enc quads, paced 256 steps ahead of encoder
        int q = item, bm = (q / 6) * 128, cq = q % 6;
        const float* pace = (bm >= 384) ? &hbuf[(size_t)(bm - 256) * HID] : nullptr;
        gemm_tile<0, 0>(emb, char_seq, enc_wih, enc_bih, nullptr, gi_enc,
                        G3, EMB, bm, (cq * 4 + sub) * 128, true, pace,
                        As[sub], Bs[sub], stid);
      } else if (item < 96) {     // gi_dec quads, paced to encoder tail
        int q = item - 48, bm = (q / 6) * 128, cq = q % 6;
        gemm_tile<0, 0>(emb, dec_in, dec_wih, dec_bih, nullptr, gi_dec,
                        G3, EMB, bm, (cq * 4 + sub) * 128, true,
                        &hbuf[(size_t)(768 + bm) * HID], As[sub], Bs[sub], stid);
      } else {                    // score quads (sentinel on hdec last row)
        int q = item - 96, rt = q / 16, cq = q % 16;
        int bn = (cq * 4 + sub) * 128;
        gemm_tile<1, 1>(hdec, nullptr, out_w, out_b, valid, out_scores,
                        VOCAB, HID, rt * 128, bn, bn < VOCAB, nullptr,
                        As[sub], Bs[sub], stid);
      }
    }
  }
}

// ---------------- states output: hdec * valid ----------------
__global__ __launch_bounds__(256) void states_kernel(
    const float* __restrict__ hdec, const float* __restrict__ valid,
    float* __restrict__ out2)
{
  int i = blockIdx.x * 256 + threadIdx.x;
  out2[i] = hdec[i] * valid[i >> 10];
}

extern "C" void kernel_launch(void* const* d_in, const int* in_sizes, int n_in,
                              void* d_out, int out_size, void* d_ws, size_t ws_size,
                              hipStream_t stream)
{
  const int*   char_seq  = (const int*)  d_in[0];
  const int*   target    = (const int*)  d_in[1];
  const float* enc_state = (const float*)d_in[2];
  const float* emb       = (const float*)d_in[3];
  const float* enc_wih   = (const float*)d_in[4];
  const float* enc_whh   = (const float*)d_in[5];
  const float* enc_bih   = (const float*)d_in[6];
  const float* enc_bhh   = (const float*)d_in[7];
  const float* dec_wih   = (const float*)d_in[8];
  const float* dec_whh   = (const float*)d_in[9];
  const float* dec_bih   = (const float*)d_in[10];
  const float* dec_bhh   = (const float*)d_in[11];
  const float* out_w     = (const float*)d_in[12];
  const float* out_b     = (const float*)d_in[13];
  const int*   sos_p     = (const int*)  d_in[14];
  const int*   eos_p     = (const int*)  d_in[15];

  char* ws = (char*)d_ws;
  float* gi_enc = (float*)ws;  ws += (size_t)SEQ_L * G3 * sizeof(float);
  float* gi_dec = (float*)ws;  ws += (size_t)SEQ_L * G3 * sizeof(float);
  float* hbuf   = (float*)ws;  ws += (size_t)(2 * SEQ_L + 1) * HID * sizeof(float);
  float* valid  = (float*)ws;  ws += SEQ_L * sizeof(float);
  int*   dec_in = (int*)ws;    ws += SEQ_L * sizeof(int);

  float* hdec = hbuf + (size_t)(SEQ_L + 1) * HID;
  float* out_scores = (float*)d_out;
  float* out_states = out_scores + (size_t)SEQ_L * VOCAB;

  prep_kernel<<<1, 1024, 0, stream>>>(target, sos_p, eos_p, dec_in, valid);
  fused_kernel<<<NWG + NWORK, 1024, 0, stream>>>(
      enc_whh, enc_bhh, dec_whh, dec_bhh, enc_state, char_seq,
      dec_in, valid, emb, enc_wih, enc_bih, dec_wih, dec_bih,
      out_w, out_b, gi_enc, gi_dec, hbuf, out_scores);
  states_kernel<<<(SEQ_L * HID) / 256, 256, 0, stream>>>(hdec, valid, out_states);
}

// Round 6
// 4224.994 us; speedup vs baseline: 1.5523x; 1.5523x over previous
//
#include <hip/hip_runtime.h>
#include <math.h>

#define VOCAB 8000
#define EMB   512
#define HID   1024
#define SEQ_L 1024
#define G3    (3*HID)
#define NWG   64          // recurrence workgroups (co-resident: 64 <= 256 CUs)
#define POISON 0xAAAAAAAAu
#define RLX __ATOMIC_RELAXED
#define AGT __HIP_MEMORY_SCOPE_AGENT

typedef float v2f __attribute__((ext_vector_type(2)));
typedef float v4f __attribute__((ext_vector_type(4)));

// 16B load that bypasses L1+L2 (reads the Infinity Cache coherence point)
__device__ __forceinline__ v4f ic_load4(const float* p) {
  v4f r;
  asm volatile("global_load_dwordx4 %0, %1, off sc0 sc1\n\ts_waitcnt vmcnt(0)"
               : "=v"(r) : "v"(p) : "memory");
  return r;
}
__device__ __forceinline__ bool any_poison4(v4f v) {
  return __float_as_uint(v.x) == POISON || __float_as_uint(v.y) == POISON ||
         __float_as_uint(v.z) == POISON || __float_as_uint(v.w) == POISON;
}
// publish with anti-poison squash (atomicExch executes at Infinity Cache)
__device__ __forceinline__ void publishf(float* p, float v) {
  if (__float_as_uint(v) == POISON) v = __uint_as_float(POISON ^ 1u);
  atomicExch(p, v);
}
// sum within each 16-lane row, VALU-only via DPP
__device__ __forceinline__ float row16_sum(float x) {
  int v = __float_as_int(x);
  x += __int_as_float(__builtin_amdgcn_update_dpp(0, v, 0xB1,  0xF, 0xF, false)); v = __float_as_int(x);
  x += __int_as_float(__builtin_amdgcn_update_dpp(0, v, 0x4E,  0xF, 0xF, false)); v = __float_as_int(x);
  x += __int_as_float(__builtin_amdgcn_update_dpp(0, v, 0x141, 0xF, 0xF, false)); v = __float_as_int(x);
  x += __int_as_float(__builtin_amdgcn_update_dpp(0, v, 0x140, 0xF, 0xF, false));
  return x;
}

// ---------------- prep: dec_in + valid mask ----------------
__global__ __launch_bounds__(1024) void prep_kernel(
    const int* __restrict__ target, const int* __restrict__ sos_p,
    const int* __restrict__ eos_p, int* __restrict__ dec_in,
    float* __restrict__ valid)
{
  int t = threadIdx.x;
  int eos = eos_p[0];
  dec_in[t] = (t == 0) ? sos_p[0] : target[t - 1];
  bool ne = (target[t] != eos);
  unsigned long long b = __ballot(ne);
  int lane = t & 63, w = t >> 6;
  __shared__ unsigned long long wb[16];
  if (lane == 0) wb[w] = b;
  __syncthreads();
  bool ok = (((~b) & ((1ull << lane) - 1ull)) == 0ull);
  for (int i = 0; i < 16; i++)
    if (i < w) ok = ok && (wb[i] == ~0ull);
  valid[t] = ok ? 1.0f : 0.0f;
}

// ---------------- fp32 NT GEMM: C[m][n] = dot(A[m][:K], B[n][:K]) + bias[n], x rowscale[m]
__global__ __launch_bounds__(256) void gemm_nt(
    const float* __restrict__ A, const int* __restrict__ idx,
    const float* __restrict__ B, const float* __restrict__ bias,
    const float* __restrict__ rowscale, float* __restrict__ C,
    int M, int N, int K)
{
  __shared__ __align__(16) float As[16][132];
  __shared__ __align__(16) float Bs[16][132];
  const int tid = threadIdx.x;
  const int bm = blockIdx.y * 128;
  const int bn = blockIdx.x * 128;
  const int tx = tid & 15, ty = tid >> 4;
  float acc[8][8];
#pragma unroll
  for (int i = 0; i < 8; i++)
#pragma unroll
    for (int jj = 0; jj < 8; jj++) acc[i][jj] = 0.f;

  for (int k0 = 0; k0 < K; k0 += 16) {
    __syncthreads();
#pragma unroll
    for (int r = 0; r < 2; r++) {
      int v = tid + 256 * r;
      int row = v >> 2;
      int kq = (v & 3) << 2;
      int m = bm + row;
      const float* abase = idx ? (A + (size_t)idx[m] * K) : (A + (size_t)m * K);
      float4 av = *(const float4*)(abase + k0 + kq);
      As[kq + 0][row] = av.x; As[kq + 1][row] = av.y;
      As[kq + 2][row] = av.z; As[kq + 3][row] = av.w;
      int n = bn + row;
      float4 bv = make_float4(0.f, 0.f, 0.f, 0.f);
      if (n < N) bv = *(const float4*)(B + (size_t)n * K + k0 + kq);
      Bs[kq + 0][row] = bv.x; Bs[kq + 1][row] = bv.y;
      Bs[kq + 2][row] = bv.z; Bs[kq + 3][row] = bv.w;
    }
    __syncthreads();
#pragma unroll
    for (int k = 0; k < 16; k++) {
      float am[8], bb[8];
      *(float4*)&am[0] = *(const float4*)&As[k][ty * 8];
      *(float4*)&am[4] = *(const float4*)&As[k][ty * 8 + 4];
      *(float4*)&bb[0] = *(const float4*)&Bs[k][tx * 8];
      *(float4*)&bb[4] = *(const float4*)&Bs[k][tx * 8 + 4];
#pragma unroll
      for (int i = 0; i < 8; i++)
#pragma unroll
        for (int jj = 0; jj < 8; jj++)
          acc[i][jj] += am[i] * bb[jj];
    }
  }
#pragma unroll
  for (int i = 0; i < 8; i++) {
    int m = bm + ty * 8 + i;
    float rs = rowscale ? rowscale[m] : 1.0f;
#pragma unroll
    for (int jj = 0; jj < 8; jj++) {
      int n = bn + tx * 8 + jj;
      if (n < N) C[(size_t)m * N + n] = (acc[i][jj] + bias[n]) * rs;
    }
  }
}

// ---------------- persistent GRU recurrence (runs ALONE on the GPU) ---------
// 64 WGs x 1024 threads. Wave w owns h element j = wg*16+w and whh rows
// {j, HID+j, 2*HID+j}; lane covers k in [lane*16, lane*16+16).
// Handoff: hbuf row s = h after s steps; publish = lane0 atomicExch (lands at
// IC); consume = 256 threads x 16B sc0/sc1 polls against the 0xAA poison the
// harness writes into d_ws. One barrier per step; DPP+2shfl reduce.
__global__ __launch_bounds__(1024, 1) void recur_kernel(
    const float* __restrict__ enc_whh, const float* __restrict__ enc_bhh,
    const float* __restrict__ dec_whh, const float* __restrict__ dec_bhh,
    const float* __restrict__ enc_state, const int* __restrict__ char_seq,
    const float* __restrict__ gi_enc, const float* __restrict__ gi_dec,
    float* hbuf)
{
  const int wg   = blockIdx.x;
  const int tid  = threadIdx.x;
  const int lane = tid & 63;
  const int w    = tid >> 6;           // wave id = owned element within slice
  const int j    = wg * 16 + w;        // owned global h index (per wave)

  __shared__ __align__(16) float hLDS[HID];

  // publish h0 slice; warm rows 1..16 into IC (no-op RMW allocates the line)
  if (lane == 0) publishf(&hbuf[j], enc_state[j]);
  if (tid >= 960 && tid < 976)
    atomicOr((unsigned int*)&hbuf[(size_t)(tid - 959) * HID + wg * 16], 0u);

  // weights -> 48 VGPRs (24 v2f) per thread
  v2f wv[3][8];
#pragma unroll
  for (int g = 0; g < 3; g++) {
    const float* wrow = enc_whh + (size_t)(g * HID + j) * HID + lane * 16;
#pragma unroll
    for (int u = 0; u < 4; u++) {
      v4f t4 = *(const v4f*)(wrow + u * 4);
      wv[g][2 * u]     = (v2f){t4.x, t4.y};
      wv[g][2 * u + 1] = (v2f){t4.z, t4.w};
    }
  }
  float bhr = enc_bhh[j], bhz = enc_bhh[HID + j], bhn = enc_bhh[2 * HID + j];

  for (int s = 1; s <= 2 * SEQ_L; s++) {
    if (s == SEQ_L + 1) {              // switch to decoder weights
#pragma unroll
      for (int g = 0; g < 3; g++) {
        const float* wrow = dec_whh + (size_t)(g * HID + j) * HID + lane * 16;
#pragma unroll
        for (int u = 0; u < 4; u++) {
          v4f t4 = *(const v4f*)(wrow + u * 4);
          wv[g][2 * u]     = (v2f){t4.x, t4.y};
          wv[g][2 * u + 1] = (v2f){t4.z, t4.w};
        }
      }
      bhr = dec_bhh[j]; bhz = dec_bhh[HID + j]; bhn = dec_bhh[2 * HID + j];
    }
    if (tid == 976 && s + 16 <= 2 * SEQ_L)
      atomicOr((unsigned int*)&hbuf[(size_t)(s + 16) * HID + wg * 16], 0u);

    // gi prefetch (plain loads; gi fully materialized by earlier dispatches)
    float gir = 0.f, giz = 0.f, gin = 0.f;
    int cs = 1;
    if (lane == 0) {
      const float* gi = (s <= SEQ_L) ? (gi_enc + (size_t)(s - 1) * G3)
                                     : (gi_dec + (size_t)(s - SEQ_L - 1) * G3);
      gir = gi[j]; giz = gi[HID + j]; gin = gi[2 * HID + j];
      if (s <= SEQ_L) cs = char_seq[s - 1];
    }
    // poll h_{s-1}: 256 threads x 16B, tight loop (no sleep), XOR-swizzled LDS store
    if (tid < 256) {
      const float* hp = hbuf + (size_t)(s - 1) * HID + 4 * tid;
      v4f hv = ic_load4(hp);
      while (any_poison4(hv)) hv = ic_load4(hp);
      int us = tid ^ ((tid >> 3) & 7);
      *(v4f*)&hLDS[us * 4] = hv;
    }
    __syncthreads();                    // the ONLY barrier per step
    int uj = j >> 2, usj = uj ^ ((uj >> 3) & 7);
    float hold = hLDS[usj * 4 + (j & 3)];
    // 48 MACs/thread on b128 LDS fragments (2-way bank aliasing = free)
    v2f acc2[3] = {(v2f){0.f, 0.f}, (v2f){0.f, 0.f}, (v2f){0.f, 0.f}};
#pragma unroll
    for (int u = 0; u < 4; u++) {
      int uu = lane * 4 + u, s2 = uu ^ ((uu >> 3) & 7);
      v4f hv = *(const v4f*)&hLDS[s2 * 4];
      v2f h0 = (v2f){hv.x, hv.y}, h1 = (v2f){hv.z, hv.w};
#pragma unroll
      for (int g = 0; g < 3; g++) {
        acc2[g] = __builtin_elementwise_fma(wv[g][2 * u], h0, acc2[g]);
        acc2[g] = __builtin_elementwise_fma(wv[g][2 * u + 1], h1, acc2[g]);
      }
    }
    // 64-lane reduce: DPP within 16 lanes, 2 shfl_xor across groups
    float gh[3];
#pragma unroll
    for (int g = 0; g < 3; g++) {
      float t = row16_sum(acc2[g].x + acc2[g].y);
      t += __shfl_xor(t, 16, 64);
      t += __shfl_xor(t, 32, 64);
      gh[g] = t;
    }
    if (lane == 0) {
      float ghr = gh[0] + bhr, ghz = gh[1] + bhz, ghn = gh[2] + bhn;
      float r = __builtin_amdgcn_rcpf(1.f + __expf(-(gir + ghr)));
      float z = __builtin_amdgcn_rcpf(1.f + __expf(-(giz + ghz)));
      float x = gin + r * ghn;
      float e = __expf(2.f * x);
      float n = 1.f - 2.f * __builtin_amdgcn_rcpf(e + 1.f);   // fast tanh
      float hnew = (1.f - z) * n + z * hold;
      if (s <= SEQ_L && cs == 0) hnew = hold;                 // encoder mask
      publishf(&hbuf[(size_t)s * HID + j], hnew);
    }
    // no second barrier: pollers can only overwrite hLDS after detecting all
    // of row s, which requires every local wave's publish, which follows that
    // wave's hLDS reads.
  }
}

// ---------------- states output: hdec * valid ----------------
__global__ __launch_bounds__(256) void states_kernel(
    const float* __restrict__ hdec, const float* __restrict__ valid,
    float* __restrict__ out2)
{
  int i = blockIdx.x * 256 + threadIdx.x;
  out2[i] = hdec[i] * valid[i >> 10];
}

extern "C" void kernel_launch(void* const* d_in, const int* in_sizes, int n_in,
                              void* d_out, int out_size, void* d_ws, size_t ws_size,
                              hipStream_t stream)
{
  const int*   char_seq  = (const int*)  d_in[0];
  const int*   target    = (const int*)  d_in[1];
  const float* enc_state = (const float*)d_in[2];
  const float* emb       = (const float*)d_in[3];
  const float* enc_wih   = (const float*)d_in[4];
  const float* enc_whh   = (const float*)d_in[5];
  const float* enc_bih   = (const float*)d_in[6];
  const float* enc_bhh   = (const float*)d_in[7];
  const float* dec_wih   = (const float*)d_in[8];
  const float* dec_whh   = (const float*)d_in[9];
  const float* dec_bih   = (const float*)d_in[10];
  const float* dec_bhh   = (const float*)d_in[11];
  const float* out_w     = (const float*)d_in[12];
  const float* out_b     = (const float*)d_in[13];
  const int*   sos_p     = (const int*)  d_in[14];
  const int*   eos_p     = (const int*)  d_in[15];

  char* ws = (char*)d_ws;
  float* gi_enc = (float*)ws;  ws += (size_t)SEQ_L * G3 * sizeof(float);
  float* gi_dec = (float*)ws;  ws += (size_t)SEQ_L * G3 * sizeof(float);
  float* hbuf   = (float*)ws;  ws += (size_t)(2 * SEQ_L + 1) * HID * sizeof(float);
  float* valid  = (float*)ws;  ws += SEQ_L * sizeof(float);
  int*   dec_in = (int*)ws;    ws += SEQ_L * sizeof(int);

  // decode step d (1..SEQ_L) writes hbuf row SEQ_L+d  ->  hdec = hbuf[SEQ_L+1]
  float* hdec = hbuf + (size_t)(SEQ_L + 1) * HID;

  float* out_scores = (float*)d_out;
  float* out_states = out_scores + (size_t)SEQ_L * VOCAB;

  prep_kernel<<<1, 1024, 0, stream>>>(target, sos_p, eos_p, dec_in, valid);
  gemm_nt<<<dim3(G3 / 128, SEQ_L / 128), 256, 0, stream>>>(
      emb, char_seq, enc_wih, enc_bih, nullptr, gi_enc, SEQ_L, G3, EMB);
  gemm_nt<<<dim3(G3 / 128, SEQ_L / 128), 256, 0, stream>>>(
      emb, dec_in, dec_wih, dec_bih, nullptr, gi_dec, SEQ_L, G3, EMB);
  recur_kernel<<<NWG, 1024, 0, stream>>>(
      enc_whh, enc_bhh, dec_whh, dec_bhh, enc_state, char_seq,
      gi_enc, gi_dec, hbuf);
  gemm_nt<<<dim3((VOCAB + 127) / 128, SEQ_L / 128), 256, 0, stream>>>(
      hdec, nullptr, out_w, out_b, valid, out_scores, SEQ_L, VOCAB, HID);
  states_kernel<<<(SEQ_L * HID) / 256, 256, 0, stream>>>(hdec, valid, out_states);
}